// Round 1
// baseline (1038.376 us; speedup 1.0000x reference)
//
#include <hip/hip_runtime.h>

typedef __attribute__((ext_vector_type(4))) float f32x4;
typedef __attribute__((ext_vector_type(2))) float f32x2;
typedef __attribute__((ext_vector_type(8))) short s16x8;
typedef __attribute__((ext_vector_type(4))) unsigned short u16x4;

static __device__ __forceinline__ unsigned short f2bf(float f) {
  unsigned int u = __builtin_bit_cast(unsigned int, f);
  u += 0x7fffu + ((u >> 16) & 1u);   // round-to-nearest-even
  return (unsigned short)(u >> 16);
}
static __device__ __forceinline__ float bf2f(unsigned short h) {
  unsigned int u = ((unsigned int)h) << 16;
  return __builtin_bit_cast(float, u);
}

static __device__ __forceinline__ void gload_lds16(const void* g, void* l) {
  __builtin_amdgcn_global_load_lds(
      (const __attribute__((address_space(1))) unsigned int*)g,
      (__attribute__((address_space(3))) unsigned int*)l, 16, 0, 0);
}

// ---------------- utility ----------------
__global__ void zero_k(int* p, int n) {
  int i = blockIdx.x * 256 + threadIdx.x;
  if (i < n) p[i] = 0;
}
__global__ void deg_count_k(const int* __restrict__ edges, int* cnt, int E) {
  int e = blockIdx.x * 256 + threadIdx.x;
  if (e < E) atomicAdd(&cnt[edges[E + e]], 1);
}
__global__ void dinv_k(const int* __restrict__ cnt, float* dinv, int N) {
  int i = blockIdx.x * 256 + threadIdx.x;
  if (i < N) dinv[i] = rsqrtf((float)(cnt[i] + 1));   // +1 self-loop
}

// ---------------- prefix scan (exclusive) over cnt -> row offsets ----------------
__global__ __launch_bounds__(256) void scan1_k(const int* __restrict__ cnt,
                                               int* __restrict__ loc,
                                               int* __restrict__ bsum, int N) {
  int t = threadIdx.x;
  int i0 = blockIdx.x * 1024 + t * 4;
  int c[4];
#pragma unroll
  for (int j = 0; j < 4; ++j) c[j] = (i0 + j < N) ? cnt[i0 + j] : 0;
  int tsum = c[0] + c[1] + c[2] + c[3];
  int lane = t & 63, wv = t >> 6;
  int incl = tsum;
#pragma unroll
  for (int off = 1; off < 64; off <<= 1) {
    int u = __shfl_up(incl, off, 64);
    if (lane >= off) incl += u;
  }
  __shared__ int ws[4];
  if (lane == 63) ws[wv] = incl;
  __syncthreads();
  int wbase = 0;
  for (int w = 0; w < wv; ++w) wbase += ws[w];
  int run = wbase + incl - tsum;
#pragma unroll
  for (int j = 0; j < 4; ++j) {
    if (i0 + j < N) loc[i0 + j] = run;
    run += c[j];
  }
  if (t == 255) bsum[blockIdx.x] = wbase + incl;
}
__global__ void scan2_k(int* bsum, int nb) {
  int lane = threadIdx.x;
  int v = (lane < nb) ? bsum[lane] : 0;
  int incl = v;
#pragma unroll
  for (int off = 1; off < 64; off <<= 1) {
    int u = __shfl_up(incl, off, 64);
    if (lane >= off) incl += u;
  }
  if (lane < nb) bsum[lane] = incl - v;
}
__global__ void addoff_k(int* loc, int* cursor, const int* __restrict__ bsum, int N) {
  int i = blockIdx.x * 256 + threadIdx.x;
  if (i < N) {
    int v = loc[i] + bsum[i >> 10];
    loc[i] = v;
    cursor[i] = v;   // cursor starts at row offset -> fill writes absolute positions
  }
}
__global__ void fill_k(const int* __restrict__ edges, int* cursor,
                       int* __restrict__ csr, int E) {
  int e = blockIdx.x * 256 + threadIdx.x;
  if (e < E) {
    int s = edges[e], d = edges[E + e];
    int pos = atomicAdd(&cursor[d], 1);
    csr[pos] = s;
  }
}

// ---------------- weight transpose + bf16 convert: Wt[n][k] = bf16(W[k][n]) ----------------
__global__ void convw_k(const float* __restrict__ W, unsigned short* __restrict__ Wt, int K, int Nn) {
  int t = blockIdx.x * 256 + threadIdx.x;
  if (t < K * Nn) {
    int n = t / K;
    int k = t - n * K;
    Wt[n * K + k] = f2bf(W[(long long)k * Nn + n]);
  }
}

// ---------------- bf16 MFMA GEMM ----------------
// Output layout is SLICE-MAJOR: outg[(col/32)*M + m][col%32] (bf16), scaled by dinv[m].
// A_BF16=false: A fp32 (layer 1, A=x). A_BF16=true: A bf16 (layer 2, A=acc1).
// B (and A when bf16) staged via global_load_lds with XOR slot swizzle:
//   content at LDS (row, slot s) = B[row][(s ^ ((row>>1)&3))*8 ..], rows of 32 shorts (64B).
template <int KTOT, int NTOT, bool A_BF16>
__global__ __launch_bounds__(256, 2) void gemm_k(
    const void* __restrict__ Aptr, const unsigned short* __restrict__ Bt,
    const float* __restrict__ dinv, unsigned short* __restrict__ outg, int M) {
  constexpr int BM = 128, BK = 32;
  constexpr int LDA = BK + 8;            // fp32-path A LDS row stride (shorts)
  constexpr int STRIP = NTOT / 4;
  constexpr int NF = STRIP / 16;
  constexpr int BCH = (NTOT / 16) / 4;   // 1KB B-chunks per wave (16 rows each)
  constexpr int ACH = (BM / 16) / 4;     // 1KB A-chunks per wave (bf16 path)
  constexpr int NT = KTOT / BK;

  __shared__ unsigned short Asm_[2][BM * LDA];
  __shared__ unsigned short Bsm_[2][NTOT * BK];

  const int tid = threadIdx.x;
  const int wave = tid >> 6;
  const int lane = tid & 63;
  const int fr = lane & 15;
  const int quad = lane >> 4;
  const int m0 = blockIdx.x * BM;

  f32x4 acc[8][NF];
#pragma unroll
  for (int i = 0; i < 8; ++i)
#pragma unroll
    for (int j = 0; j < NF; ++j) { f32x4 z = {0.f, 0.f, 0.f, 0.f}; acc[i][j] = z; }

  // stage helpers: lane -> (row-in-chunk, swizzled source slot)
  const int sl_r = lane >> 2;
  const int sl_s = (lane & 3) ^ ((lane >> 3) & 3);

  auto stageB = [&](int k0, int buf) {
#pragma unroll
    for (int c = 0; c < BCH; ++c) {
      int cc = wave * BCH + c;
      int r = cc * 16 + sl_r;
      const unsigned short* gp = Bt + (long long)r * KTOT + k0 + sl_s * 8;
      gload_lds16(gp, &Bsm_[buf][cc * 512]);
    }
  };
  auto stageA_h = [&](int k0, int buf) {
    const unsigned short* Ah = (const unsigned short*)Aptr;
#pragma unroll
    for (int c = 0; c < ACH; ++c) {
      int cc = wave * ACH + c;
      int r = cc * 16 + sl_r;
      const unsigned short* gp = Ah + (long long)(m0 + r) * KTOT + k0 + sl_s * 8;
      gload_lds16(gp, &Asm_[buf][cc * 512]);
    }
  };

  // fp32 A path: regs -> convert -> ds_write (padded layout, conflict-free)
  const int sr = tid >> 1;
  const int sc = (tid & 1) << 4;
  const bool arow_ok = (m0 + sr) < M;
  const float* arowf = (const float*)Aptr + (long long)(m0 + sr) * KTOT;
  float va[16];
  auto loadA = [&](int k0) {
    if (arow_ok) {
      const f32x4* p = (const f32x4*)(arowf + k0 + sc);
      f32x4 v0 = p[0], v1 = p[1], v2 = p[2], v3 = p[3];
#pragma unroll
      for (int j = 0; j < 4; ++j) { va[j] = v0[j]; va[4 + j] = v1[j]; va[8 + j] = v2[j]; va[12 + j] = v3[j]; }
    } else {
#pragma unroll
      for (int j = 0; j < 16; ++j) va[j] = 0.0f;
    }
  };
  auto cvtWriteA = [&](int buf) {
    s16x8 h0, h1;
#pragma unroll
    for (int j = 0; j < 8; ++j) { h0[j] = (short)f2bf(va[j]); h1[j] = (short)f2bf(va[8 + j]); }
    *(s16x8*)&Asm_[buf][sr * LDA + sc] = h0;
    *(s16x8*)&Asm_[buf][sr * LDA + sc + 8] = h1;
  };

  // prologue: stage tile 0
  stageB(0, 0);
  if constexpr (A_BF16) {
    stageA_h(0, 0);
  } else {
    loadA(0);
    cvtWriteA(0);
    if (NT > 1) loadA(BK);
  }

  const int xsl = (fr >> 1) & 3;
  for (int kt = 0; kt < NT; ++kt) {
    const int cur = kt & 1;
    __syncthreads();   // drains vm (stage of cur) + lgkm (A writes of cur)
    if (kt + 1 < NT) {
      stageB((kt + 1) * BK, cur ^ 1);
      if constexpr (A_BF16) {
        stageA_h((kt + 1) * BK, cur ^ 1);
      } else {
        cvtWriteA(cur ^ 1);                    // consumes va(kt+1)
        if (kt + 2 < NT) loadA((kt + 2) * BK); // prefetch next-next
      }
    }

    s16x8 af[8], bfr[NF];
#pragma unroll
    for (int mi = 0; mi < 8; ++mi) {
      if constexpr (A_BF16)
        af[mi] = *(const s16x8*)&Asm_[cur][(mi * 16 + fr) * BK + ((quad ^ xsl) << 3)];
      else
        af[mi] = *(const s16x8*)&Asm_[cur][(mi * 16 + fr) * LDA + quad * 8];
    }
#pragma unroll
    for (int ni = 0; ni < NF; ++ni)
      bfr[ni] = *(const s16x8*)&Bsm_[cur][(wave * STRIP + ni * 16 + fr) * BK + ((quad ^ xsl) << 3)];
#pragma unroll
    for (int mi = 0; mi < 8; ++mi)
#pragma unroll
      for (int ni = 0; ni < NF; ++ni)
        acc[mi][ni] = __builtin_amdgcn_mfma_f32_16x16x32_bf16(af[mi], bfr[ni], acc[mi][ni], 0, 0, 0);
  }

  // epilogue: C/D layout col=lane&15, row=quad*4+r; write slice-major
#pragma unroll
  for (int mi = 0; mi < 8; ++mi) {
    int mbase = mi * 16 + quad * 4;
#pragma unroll
    for (int r = 0; r < 4; ++r) {
      int gm = m0 + mbase + r;
      if (gm < M) {
        float dv = dinv[gm];
#pragma unroll
        for (int ni = 0; ni < NF; ++ni) {
          int col = wave * STRIP + ni * 16 + fr;
          long long addr = ((long long)(col >> 5) * M + gm) * 32 + (col & 31);
          outg[addr] = f2bf(acc[mi][ni][r] * dv);
        }
      }
    }
  }
}

// ---------------- sliced aggregation ----------------
// Gather table g is slice-major: [F/32][N][32] bf16 (3.2 MB per slice -> per-XCD L2 resident).
// Wave = 8 nodes x 8 lanes; each lane covers 4 features of the 32-feature slice.
// L1=true : out bf16 node-major [N][F], relu(b + dinv*sum)
// L1=false: out fp32 node-major [N][F],       b + dinv*sum   (normalized later)
template <int F, bool L1>
__global__ __launch_bounds__(256) void aggs_k(const int* __restrict__ csr,
                                              const int* __restrict__ row,
                                              const int* __restrict__ cnt,
                                              const unsigned short* __restrict__ g,
                                              const float* __restrict__ bias,
                                              const float* __restrict__ dinv,
                                              void* __restrict__ outp, int N) {
  const int wave = threadIdx.x >> 6, lane = threadIdx.x & 63;
  const int grp = lane >> 3, sub = lane & 7;
  const int node = blockIdx.x * 32 + wave * 8 + grp;
  const bool ok = node < N;
  const int nn = ok ? node : 0;
  const int s = blockIdx.y;
  const unsigned short* tbl = g + (long long)s * N * 32;
  const int fo = sub * 4;

  u16x4 sv = *(const u16x4*)&tbl[(long long)nn * 32 + fo];   // self row
  f32x4 acc = {bf2f(sv[0]), bf2f(sv[1]), bf2f(sv[2]), bf2f(sv[3])};

  int start = ok ? row[nn] : 0;
  int len = ok ? cnt[nn] : 0;
  int ml = len;
  ml = max(ml, __shfl_xor(ml, 8, 64));
  ml = max(ml, __shfl_xor(ml, 16, 64));
  ml = max(ml, __shfl_xor(ml, 32, 64));

  for (int j = 0; j < ml; j += 4) {
    int idx[4];
#pragma unroll
    for (int t = 0; t < 4; ++t) {
      int jt = j + t;
      int p = start + ((jt < len) ? jt : 0);
      int raw = __builtin_nontemporal_load(&csr[p]);
      idx[t] = (jt < len) ? raw : 0;     // clamp garbage -> valid row 0 (zero-weighted)
    }
    u16x4 v[4];
#pragma unroll
    for (int t = 0; t < 4; ++t) v[t] = *(const u16x4*)&tbl[(long long)idx[t] * 32 + fo];
#pragma unroll
    for (int t = 0; t < 4; ++t) {
      float m = ((j + t) < len) ? 1.0f : 0.0f;
#pragma unroll
      for (int k = 0; k < 4; ++k) acc[k] += m * bf2f(v[t][k]);
    }
  }

  if (ok) {
    float dv = dinv[node];
    f32x4 b = *(const f32x4*)&bias[s * 32 + fo];
    if constexpr (L1) {
      u16x4 o;
#pragma unroll
      for (int k = 0; k < 4; ++k) o[k] = f2bf(fmaxf(0.0f, b[k] + dv * acc[k]));
      __builtin_nontemporal_store(o, (u16x4*)&((unsigned short*)outp)[(long long)node * F + s * 32 + fo]);
    } else {
      f32x4 o;
#pragma unroll
      for (int k = 0; k < 4; ++k) o[k] = b[k] + dv * acc[k];
      __builtin_nontemporal_store(o, (f32x4*)&((float*)outp)[(long long)node * F + s * 32 + fo]);
    }
  }
}

// ---------------- final L2 normalize: out = pre / max(||pre||, 1e-12) ----------------
__global__ __launch_bounds__(256) void norm_k(const float* __restrict__ pre,
                                              float* __restrict__ out, int N) {
  int node = blockIdx.x * 4 + (threadIdx.x >> 6);
  if (node >= N) return;
  int lane = threadIdx.x & 63;
  f32x2 v = *(const f32x2*)&pre[(long long)node * 128 + lane * 2];
  float ss = v[0] * v[0] + v[1] * v[1];
#pragma unroll
  for (int off = 32; off > 0; off >>= 1) ss += __shfl_xor(ss, off, 64);
  float inv = 1.0f / fmaxf(sqrtf(ss), 1e-12f);
  f32x2 o = {v[0] * inv, v[1] * inv};
  *(f32x2*)&out[(long long)node * 128 + lane * 2] = o;
}

extern "C" void kernel_launch(void* const* d_in, const int* in_sizes, int n_in,
                              void* d_out, int out_size, void* d_ws, size_t ws_size,
                              hipStream_t stream) {
  const float* x = (const float*)d_in[0];
  const int* edges = (const int*)d_in[1];
  const float* W1 = (const float*)d_in[2];
  const float* b1 = (const float*)d_in[3];
  const float* W2 = (const float*)d_in[4];
  const float* b2 = (const float*)d_in[5];
  float* out = (float*)d_out;

  const int HID = in_sizes[3];          // 256
  const int OUT = in_sizes[5];          // 128
  const int IN = in_sizes[2] / HID;     // 1536
  const int N = in_sizes[0] / IN;       // 50000
  const int E = in_sizes[1] / 2;        // 1600000

  size_t off = 0;
  auto carve = [&](size_t bytes) {
    void* p = (char*)d_ws + off;
    off += (bytes + 255) & ~(size_t)255;
    return p;
  };
  int* cnt = (int*)carve((size_t)N * 4);
  int* cursor = (int*)carve((size_t)N * 4);
  int* row = (int*)carve((size_t)N * 4);
  int* bsum = (int*)carve(64 * 4);
  int* csr = (int*)carve((size_t)E * 4 + 1024);   // +pad: clamped OOB reads land in-bounds
  float* dinv = (float*)carve((size_t)N * 4);
  unsigned short* W1t = (unsigned short*)carve((size_t)IN * HID * 2);
  unsigned short* W2t = (unsigned short*)carve((size_t)HID * OUT * 2);
  unsigned short* g1 = (unsigned short*)carve((size_t)N * HID * 2);    // slice-major [8][N][32]
  unsigned short* acc1 = (unsigned short*)carve((size_t)N * HID * 2);  // node-major  [N][256]
  unsigned short* g2 = (unsigned short*)carve((size_t)N * OUT * 2);    // slice-major [4][N][32]
  float* pre = (float*)carve((size_t)N * OUT * 4);                     // node-major  [N][128]
  (void)ws_size; (void)n_in; (void)out_size;

  const int nb = (N + 1023) / 1024;

  zero_k<<<(N + 255) / 256, 256, 0, stream>>>(cnt, N);
  deg_count_k<<<(E + 255) / 256, 256, 0, stream>>>(edges, cnt, E);
  dinv_k<<<(N + 255) / 256, 256, 0, stream>>>(cnt, dinv, N);

  scan1_k<<<nb, 256, 0, stream>>>(cnt, row, bsum, N);
  scan2_k<<<1, 64, 0, stream>>>(bsum, nb);
  addoff_k<<<(N + 255) / 256, 256, 0, stream>>>(row, cursor, bsum, N);
  fill_k<<<(E + 255) / 256, 256, 0, stream>>>(edges, cursor, csr, E);

  convw_k<<<(IN * HID + 255) / 256, 256, 0, stream>>>(W1, W1t, IN, HID);
  convw_k<<<(HID * OUT + 255) / 256, 256, 0, stream>>>(W2, W2t, HID, OUT);

  int mtiles = (N + 127) / 128;
  int nb32 = (N + 31) / 32;
  gemm_k<1536, 256, false><<<mtiles, 256, 0, stream>>>(x, W1t, dinv, g1, N);
  aggs_k<256, true><<<dim3(nb32, 8), 256, 0, stream>>>(csr, row, cnt, g1, b1, dinv, acc1, N);
  gemm_k<256, 128, true><<<mtiles, 256, 0, stream>>>(acc1, W2t, dinv, g2, N);
  aggs_k<128, false><<<dim3(nb32, 4), 256, 0, stream>>>(csr, row, cnt, g2, b2, dinv, pre, N);
  norm_k<<<(N + 3) / 4, 256, 0, stream>>>(pre, out, N);
}

// Round 2
// 844.996 us; speedup vs baseline: 1.2289x; 1.2289x over previous
//
#include <hip/hip_runtime.h>

typedef __attribute__((ext_vector_type(4))) float f32x4;
typedef __attribute__((ext_vector_type(2))) float f32x2;
typedef __attribute__((ext_vector_type(8))) short s16x8;
typedef __attribute__((ext_vector_type(4))) unsigned short u16x4;

static __device__ __forceinline__ unsigned short f2bf(float f) {
  unsigned int u = __builtin_bit_cast(unsigned int, f);
  u += 0x7fffu + ((u >> 16) & 1u);   // round-to-nearest-even
  return (unsigned short)(u >> 16);
}
static __device__ __forceinline__ float bf2f(unsigned short h) {
  unsigned int u = ((unsigned int)h) << 16;
  return __builtin_bit_cast(float, u);
}

static __device__ __forceinline__ void gload_lds16(const void* g, void* l) {
  __builtin_amdgcn_global_load_lds(
      (const __attribute__((address_space(1))) unsigned int*)g,
      (__attribute__((address_space(3))) unsigned int*)l, 16, 0, 0);
}

// ---------------- utility ----------------
__global__ void zero_k(int* p, int n) {
  int i = blockIdx.x * 256 + threadIdx.x;
  if (i < n) p[i] = 0;
}
__global__ void deg_count_k(const int* __restrict__ edges, int* cnt, int E) {
  int e = blockIdx.x * 256 + threadIdx.x;
  if (e < E) atomicAdd(&cnt[edges[E + e]], 1);
}
__global__ void dinv_k(const int* __restrict__ cnt, float* dinv, int N) {
  int i = blockIdx.x * 256 + threadIdx.x;
  if (i < N) dinv[i] = rsqrtf((float)(cnt[i] + 1));   // +1 self-loop
}

// ---------------- prefix scan (exclusive) over cnt -> row offsets ----------------
__global__ __launch_bounds__(256) void scan1_k(const int* __restrict__ cnt,
                                               int* __restrict__ loc,
                                               int* __restrict__ bsum, int N) {
  int t = threadIdx.x;
  int i0 = blockIdx.x * 1024 + t * 4;
  int c[4];
#pragma unroll
  for (int j = 0; j < 4; ++j) c[j] = (i0 + j < N) ? cnt[i0 + j] : 0;
  int tsum = c[0] + c[1] + c[2] + c[3];
  int lane = t & 63, wv = t >> 6;
  int incl = tsum;
#pragma unroll
  for (int off = 1; off < 64; off <<= 1) {
    int u = __shfl_up(incl, off, 64);
    if (lane >= off) incl += u;
  }
  __shared__ int ws[4];
  if (lane == 63) ws[wv] = incl;
  __syncthreads();
  int wbase = 0;
  for (int w = 0; w < wv; ++w) wbase += ws[w];
  int run = wbase + incl - tsum;
#pragma unroll
  for (int j = 0; j < 4; ++j) {
    if (i0 + j < N) loc[i0 + j] = run;
    run += c[j];
  }
  if (t == 255) bsum[blockIdx.x] = wbase + incl;
}
__global__ void scan2_k(int* bsum, int nb) {
  int lane = threadIdx.x;
  int v = (lane < nb) ? bsum[lane] : 0;
  int incl = v;
#pragma unroll
  for (int off = 1; off < 64; off <<= 1) {
    int u = __shfl_up(incl, off, 64);
    if (lane >= off) incl += u;
  }
  if (lane < nb) bsum[lane] = incl - v;
}
__global__ void addoff_k(int* loc, int* cursor, const int* __restrict__ bsum, int N) {
  int i = blockIdx.x * 256 + threadIdx.x;
  if (i < N) {
    int v = loc[i] + bsum[i >> 10];
    loc[i] = v;
    cursor[i] = v;   // cursor starts at row offset -> fill writes absolute positions
  }
}
__global__ void fill_k(const int* __restrict__ edges, int* cursor,
                       int* __restrict__ csr, int E) {
  int e = blockIdx.x * 256 + threadIdx.x;
  if (e < E) {
    int s = edges[e], d = edges[E + e];
    int pos = atomicAdd(&cursor[d], 1);
    csr[pos] = s;
  }
}

// ---------------- weight transpose + bf16 convert: Wt[n][k] = bf16(W[k][n]) ----------------
__global__ void convw_k(const float* __restrict__ W, unsigned short* __restrict__ Wt, int K, int Nn) {
  int t = blockIdx.x * 256 + threadIdx.x;
  if (t < K * Nn) {
    int n = t / K;
    int k = t - n * K;
    Wt[n * K + k] = f2bf(W[(long long)k * Nn + n]);
  }
}

// ---------------- bf16 MFMA GEMM ----------------
// Output NODE-MAJOR: outg[m][n] = bf16( dinv[m] * (A @ Bt^T)[m][n] ).
// A_BF16=false: A fp32 (layer 1, A=x). A_BF16=true: A bf16 (layer 2, A=acc1).
// B (and A when bf16) staged via global_load_lds with XOR slot swizzle:
//   content at LDS (row, slot s) = B[row][(s ^ ((row>>1)&3))*8 ..], rows of 32 shorts (64B).
template <int KTOT, int NTOT, bool A_BF16>
__global__ __launch_bounds__(256, 2) void gemm_k(
    const void* __restrict__ Aptr, const unsigned short* __restrict__ Bt,
    const float* __restrict__ dinv, unsigned short* __restrict__ outg, int M) {
  constexpr int BM = 128, BK = 32;
  constexpr int LDA = BK + 8;            // fp32-path A LDS row stride (shorts)
  constexpr int STRIP = NTOT / 4;
  constexpr int NF = STRIP / 16;
  constexpr int BCH = (NTOT / 16) / 4;   // 1KB B-chunks per wave (16 rows each)
  constexpr int ACH = (BM / 16) / 4;     // 1KB A-chunks per wave (bf16 path)
  constexpr int NT = KTOT / BK;

  __shared__ unsigned short Asm_[2][BM * LDA];
  __shared__ unsigned short Bsm_[2][NTOT * BK];

  const int tid = threadIdx.x;
  const int wave = tid >> 6;
  const int lane = tid & 63;
  const int fr = lane & 15;
  const int quad = lane >> 4;
  const int m0 = blockIdx.x * BM;

  f32x4 acc[8][NF];
#pragma unroll
  for (int i = 0; i < 8; ++i)
#pragma unroll
    for (int j = 0; j < NF; ++j) { f32x4 z = {0.f, 0.f, 0.f, 0.f}; acc[i][j] = z; }

  // stage helpers: lane -> (row-in-chunk, swizzled source slot)
  const int sl_r = lane >> 2;
  const int sl_s = (lane & 3) ^ ((lane >> 3) & 3);

  auto stageB = [&](int k0, int buf) {
#pragma unroll
    for (int c = 0; c < BCH; ++c) {
      int cc = wave * BCH + c;
      int r = cc * 16 + sl_r;
      const unsigned short* gp = Bt + (long long)r * KTOT + k0 + sl_s * 8;
      gload_lds16(gp, &Bsm_[buf][cc * 512]);
    }
  };
  auto stageA_h = [&](int k0, int buf) {
    const unsigned short* Ah = (const unsigned short*)Aptr;
#pragma unroll
    for (int c = 0; c < ACH; ++c) {
      int cc = wave * ACH + c;
      int r = cc * 16 + sl_r;
      const unsigned short* gp = Ah + (long long)(m0 + r) * KTOT + k0 + sl_s * 8;
      gload_lds16(gp, &Asm_[buf][cc * 512]);
    }
  };

  // fp32 A path: regs -> convert -> ds_write (padded layout, conflict-free)
  const int sr = tid >> 1;
  const int sc = (tid & 1) << 4;
  const bool arow_ok = (m0 + sr) < M;
  const float* arowf = (const float*)Aptr + (long long)(m0 + sr) * KTOT;
  float va[16];
  auto loadA = [&](int k0) {
    if (arow_ok) {
      const f32x4* p = (const f32x4*)(arowf + k0 + sc);
      f32x4 v0 = p[0], v1 = p[1], v2 = p[2], v3 = p[3];
#pragma unroll
      for (int j = 0; j < 4; ++j) { va[j] = v0[j]; va[4 + j] = v1[j]; va[8 + j] = v2[j]; va[12 + j] = v3[j]; }
    } else {
#pragma unroll
      for (int j = 0; j < 16; ++j) va[j] = 0.0f;
    }
  };
  auto cvtWriteA = [&](int buf) {
    s16x8 h0, h1;
#pragma unroll
    for (int j = 0; j < 8; ++j) { h0[j] = (short)f2bf(va[j]); h1[j] = (short)f2bf(va[8 + j]); }
    *(s16x8*)&Asm_[buf][sr * LDA + sc] = h0;
    *(s16x8*)&Asm_[buf][sr * LDA + sc + 8] = h1;
  };

  // prologue: stage tile 0
  stageB(0, 0);
  if constexpr (A_BF16) {
    stageA_h(0, 0);
  } else {
    loadA(0);
    cvtWriteA(0);
    if (NT > 1) loadA(BK);
  }

  const int xsl = (fr >> 1) & 3;
  for (int kt = 0; kt < NT; ++kt) {
    const int cur = kt & 1;
    __syncthreads();   // drains vm (stage of cur) + lgkm (A writes of cur)
    if (kt + 1 < NT) {
      stageB((kt + 1) * BK, cur ^ 1);
      if constexpr (A_BF16) {
        stageA_h((kt + 1) * BK, cur ^ 1);
      } else {
        cvtWriteA(cur ^ 1);                    // consumes va(kt+1)
        if (kt + 2 < NT) loadA((kt + 2) * BK); // prefetch next-next
      }
    }

    s16x8 af[8], bfr[NF];
#pragma unroll
    for (int mi = 0; mi < 8; ++mi) {
      if constexpr (A_BF16)
        af[mi] = *(const s16x8*)&Asm_[cur][(mi * 16 + fr) * BK + ((quad ^ xsl) << 3)];
      else
        af[mi] = *(const s16x8*)&Asm_[cur][(mi * 16 + fr) * LDA + quad * 8];
    }
#pragma unroll
    for (int ni = 0; ni < NF; ++ni)
      bfr[ni] = *(const s16x8*)&Bsm_[cur][(wave * STRIP + ni * 16 + fr) * BK + ((quad ^ xsl) << 3)];
#pragma unroll
    for (int mi = 0; mi < 8; ++mi)
#pragma unroll
      for (int ni = 0; ni < NF; ++ni)
        acc[mi][ni] = __builtin_amdgcn_mfma_f32_16x16x32_bf16(af[mi], bfr[ni], acc[mi][ni], 0, 0, 0);
  }

  // epilogue: C/D layout col=lane&15, row=quad*4+r; write node-major
#pragma unroll
  for (int mi = 0; mi < 8; ++mi) {
    int mbase = mi * 16 + quad * 4;
#pragma unroll
    for (int r = 0; r < 4; ++r) {
      int gm = m0 + mbase + r;
      if (gm < M) {
        float dv = dinv[gm];
#pragma unroll
        for (int ni = 0; ni < NF; ++ni) {
          int col = wave * STRIP + ni * 16 + fr;
          outg[(long long)gm * NTOT + col] = f2bf(acc[mi][ni][r] * dv);
        }
      }
    }
  }
}

// ---------------- agg layer 1 (node-major, 2 nodes/wave, 16B gathers) ----------------
// acc1[d][0..256) = bf16(relu(b1 + dinv[d]*(g[d] + sum g[src])))
__global__ __launch_bounds__(256) void agg1_k(const int* __restrict__ csr,
                                              const int* __restrict__ row,
                                              const int* __restrict__ cnt,
                                              const unsigned short* __restrict__ g,
                                              const float* __restrict__ bias,
                                              const float* __restrict__ dinv,
                                              unsigned short* __restrict__ h, int N) {
  const int wave = threadIdx.x >> 6, lane = threadIdx.x & 63;
  const int grp = lane >> 5, sub = lane & 31;     // 2 nodes per wave
  const int node = blockIdx.x * 8 + wave * 2 + grp;
  if (node >= N) return;
  const int f0 = sub * 8;                         // 8 feats = 16B per lane
  s16x8 sv = *(const s16x8*)&g[(long long)node * 256 + f0];
  float s[8];
#pragma unroll
  for (int k = 0; k < 8; ++k) s[k] = bf2f((unsigned short)sv[k]);
  const int start = row[node], len = cnt[node];
  int j = 0;
  for (; j + 8 <= len; j += 8) {
    int idx[8];
#pragma unroll
    for (int t = 0; t < 8; ++t) idx[t] = csr[start + j + t];
    s16x8 v[8];
#pragma unroll
    for (int t = 0; t < 8; ++t) v[t] = *(const s16x8*)&g[(long long)idx[t] * 256 + f0];
#pragma unroll
    for (int t = 0; t < 8; ++t)
#pragma unroll
      for (int k = 0; k < 8; ++k) s[k] += bf2f((unsigned short)v[t][k]);
  }
  for (; j < len; ++j) {
    int i0 = csr[start + j];
    s16x8 v = *(const s16x8*)&g[(long long)i0 * 256 + f0];
#pragma unroll
    for (int k = 0; k < 8; ++k) s[k] += bf2f((unsigned short)v[k]);
  }
  const float dv = dinv[node];
  f32x4 b0 = *(const f32x4*)&bias[f0];
  f32x4 b1v = *(const f32x4*)&bias[f0 + 4];
  s16x8 o;
#pragma unroll
  for (int k = 0; k < 4; ++k) o[k] = (short)f2bf(fmaxf(0.0f, b0[k] + dv * s[k]));
#pragma unroll
  for (int k = 0; k < 4; ++k) o[4 + k] = (short)f2bf(fmaxf(0.0f, b1v[k] + dv * s[4 + k]));
  *(s16x8*)&h[(long long)node * 256 + f0] = o;
}

// ---------------- agg layer 2 + L2-normalize fused (4 nodes/wave, 16B gathers) ----------------
__global__ __launch_bounds__(256) void agg2_k(const int* __restrict__ csr,
                                              const int* __restrict__ row,
                                              const int* __restrict__ cnt,
                                              const unsigned short* __restrict__ g,
                                              const float* __restrict__ b2,
                                              const float* __restrict__ dinv,
                                              float* __restrict__ out, int N) {
  const int wave = threadIdx.x >> 6, lane = threadIdx.x & 63;
  const int grp = lane >> 4, sub = lane & 15;     // 4 nodes per wave
  const int node = blockIdx.x * 16 + wave * 4 + grp;
  if (node >= N) return;
  const int f0 = sub * 8;                         // 8 feats = 16B per lane
  s16x8 sv = *(const s16x8*)&g[(long long)node * 128 + f0];
  float s[8];
#pragma unroll
  for (int k = 0; k < 8; ++k) s[k] = bf2f((unsigned short)sv[k]);
  const int start = row[node], len = cnt[node];
  int j = 0;
  for (; j + 8 <= len; j += 8) {
    int idx[8];
#pragma unroll
    for (int t = 0; t < 8; ++t) idx[t] = csr[start + j + t];
    s16x8 v[8];
#pragma unroll
    for (int t = 0; t < 8; ++t) v[t] = *(const s16x8*)&g[(long long)idx[t] * 128 + f0];
#pragma unroll
    for (int t = 0; t < 8; ++t)
#pragma unroll
      for (int k = 0; k < 8; ++k) s[k] += bf2f((unsigned short)v[t][k]);
  }
  for (; j < len; ++j) {
    int i0 = csr[start + j];
    s16x8 v = *(const s16x8*)&g[(long long)i0 * 128 + f0];
#pragma unroll
    for (int k = 0; k < 8; ++k) s[k] += bf2f((unsigned short)v[k]);
  }
  const float dv = dinv[node];
  f32x4 b0 = *(const f32x4*)&b2[f0];
  f32x4 b1v = *(const f32x4*)&b2[f0 + 4];
  float x[8];
#pragma unroll
  for (int k = 0; k < 4; ++k) x[k] = b0[k] + dv * s[k];
#pragma unroll
  for (int k = 0; k < 4; ++k) x[4 + k] = b1v[k] + dv * s[4 + k];
  float ss = 0.0f;
#pragma unroll
  for (int k = 0; k < 8; ++k) ss += x[k] * x[k];
  // reduce across the 16-lane group
#pragma unroll
  for (int off = 1; off < 16; off <<= 1) ss += __shfl_xor(ss, off, 64);
  const float inv = 1.0f / fmaxf(sqrtf(ss), 1e-12f);
  f32x4 o0 = {x[0] * inv, x[1] * inv, x[2] * inv, x[3] * inv};
  f32x4 o1 = {x[4] * inv, x[5] * inv, x[6] * inv, x[7] * inv};
  *(f32x4*)&out[(long long)node * 128 + f0] = o0;
  *(f32x4*)&out[(long long)node * 128 + f0 + 4] = o1;
}

extern "C" void kernel_launch(void* const* d_in, const int* in_sizes, int n_in,
                              void* d_out, int out_size, void* d_ws, size_t ws_size,
                              hipStream_t stream) {
  const float* x = (const float*)d_in[0];
  const int* edges = (const int*)d_in[1];
  const float* W1 = (const float*)d_in[2];
  const float* b1 = (const float*)d_in[3];
  const float* W2 = (const float*)d_in[4];
  const float* b2 = (const float*)d_in[5];
  float* out = (float*)d_out;

  const int HID = in_sizes[3];          // 256
  const int OUT = in_sizes[5];          // 128
  const int IN = in_sizes[2] / HID;     // 1536
  const int N = in_sizes[0] / IN;       // 50000
  const int E = in_sizes[1] / 2;        // 1600000

  size_t off = 0;
  auto carve = [&](size_t bytes) {
    void* p = (char*)d_ws + off;
    off += (bytes + 255) & ~(size_t)255;
    return p;
  };
  int* cnt = (int*)carve((size_t)N * 4);
  int* cursor = (int*)carve((size_t)N * 4);
  int* row = (int*)carve((size_t)N * 4);
  int* bsum = (int*)carve(64 * 4);
  int* csr = (int*)carve((size_t)E * 4 + 1024);
  float* dinv = (float*)carve((size_t)N * 4);
  unsigned short* W1t = (unsigned short*)carve((size_t)IN * HID * 2);
  unsigned short* W2t = (unsigned short*)carve((size_t)HID * OUT * 2);
  unsigned short* g1 = (unsigned short*)carve((size_t)N * HID * 2);    // node-major [N][256]
  unsigned short* acc1 = (unsigned short*)carve((size_t)N * HID * 2);  // node-major [N][256]
  unsigned short* g2 = (unsigned short*)carve((size_t)N * OUT * 2);    // node-major [N][128]
  (void)ws_size; (void)n_in; (void)out_size;

  const int nb = (N + 1023) / 1024;

  zero_k<<<(N + 255) / 256, 256, 0, stream>>>(cnt, N);
  deg_count_k<<<(E + 255) / 256, 256, 0, stream>>>(edges, cnt, E);
  dinv_k<<<(N + 255) / 256, 256, 0, stream>>>(cnt, dinv, N);

  scan1_k<<<nb, 256, 0, stream>>>(cnt, row, bsum, N);
  scan2_k<<<1, 64, 0, stream>>>(bsum, nb);
  addoff_k<<<(N + 255) / 256, 256, 0, stream>>>(row, cursor, bsum, N);
  fill_k<<<(E + 255) / 256, 256, 0, stream>>>(edges, cursor, csr, E);

  convw_k<<<(IN * HID + 255) / 256, 256, 0, stream>>>(W1, W1t, IN, HID);
  convw_k<<<(HID * OUT + 255) / 256, 256, 0, stream>>>(W2, W2t, HID, OUT);

  int mtiles = (N + 127) / 128;
  gemm_k<1536, 256, false><<<mtiles, 256, 0, stream>>>(x, W1t, dinv, g1, N);
  agg1_k<<<(N + 7) / 8, 256, 0, stream>>>(csr, row, cnt, g1, b1, dinv, acc1, N);
  gemm_k<256, 128, true><<<mtiles, 256, 0, stream>>>(acc1, W2t, dinv, g2, N);
  agg2_k<<<(N + 15) / 16, 256, 0, stream>>>(csr, row, cnt, g2, b2, dinv, out, N);
}